// Round 12
// baseline (85.454 us; speedup 1.0000x reference)
//
#include <hip/hip_runtime.h>
#include <math.h>

// DETR loss with per-batch Hungarian matching (Jonker-Volgenant, exact).
//
// One block = one wave (64 lanes) per batch; lane t owns cost column t+1
// (pred t) and compacted row t+1. All matcher state in registers.
// Pipeline (decisions bit-identical to r7/r8/r10/r11 -- absmax 0.0):
//   1. cost build (gt rows via readlane; row index from SALU iteration of
//      the validity mask) + fused row-reduction claims (u[i]=rowmin, v=0,
//      argmin-column claims first-come; valid rectangular dual).
//      ROUND 12: 2-row unrolled -- rows are independent, so two
//      readlane/abs/add/DPP streams interleave for ILP at 1-wave occupancy;
//      claims remain in original row order (bit-identical).
//   2. Dijkstra phases for contested rows. ROUND 12: key-first restructure
//      -- the u32 argmin key of minv is maintained across iterations
//      (recomputed in the ds_read shadow); per iteration only cur's key is
//      computed before the DPP chain, and the f64 minv/way merge runs in
//      the chain's shadow. Strictly monotone key map => merge-by-key ==
//      merge-by-value; decisions bit-identical, ~12cy off the serial path.
//   3. Reducer block (blockIdx == B): spin-waits per-batch MAGIC flags
//      (agent scope release/acquire), accumulates losses as they land,
//      overlapping the final mean with match execution (r11-verified).

#define SS 64
#define MAGIC 0x13579BDFu
#define LDS_FENCE() asm volatile("s_waitcnt lgkmcnt(0)" ::: "memory")

__device__ __forceinline__ int rlane_i(int x, int lane) {
    return __builtin_amdgcn_readlane(x, lane);
}
__device__ __forceinline__ double rlane_d(double x, int lane) {
    return __hiloint2double(rlane_i(__double2hiint(x), lane),
                            rlane_i(__double2loint(x), lane));
}

// One min step; old = x -> GCNDPPCombine folds to v_min_u32_dpp.
template<int CTRL>
__device__ __forceinline__ unsigned mstep(unsigned x) {
    const unsigned y = (unsigned)__builtin_amdgcn_update_dpp(
        (int)x, (int)x, CTRL, 0xF, 0xF, false);
    return x < y ? x : y;
}
// After this, lane 63 holds the u32 min over all 64 lanes.
__device__ __forceinline__ unsigned wave_min_u32_to63(unsigned x) {
    x = mstep<0x111>(x);  // row_shr:1
    x = mstep<0x112>(x);  // row_shr:2
    x = mstep<0x114>(x);  // row_shr:4
    x = mstep<0x118>(x);  // row_shr:8
    x = mstep<0x142>(x);  // row_bcast15
    x = mstep<0x143>(x);  // row_bcast31
    return x;
}

// Order-preserving u32 key of the f64 hi-word (strictly monotone in value;
// equal keys <=> equal hi-words).
__device__ __forceinline__ unsigned f64hi_key(double x) {
    const int hi  = __double2hiint(x);
    const int s31 = hi >> 31;
    return (unsigned)(hi ^ (s31 | (int)0x80000000));
}

__global__ __launch_bounds__(64) void detr_match_loss_kernel(
    const float* __restrict__ pred_strokes,   // [B,64,10]
    const float* __restrict__ pred_validity,  // [B,64,1]
    const float* __restrict__ targets,        // [B,64,11]
    double* __restrict__ loss_ws,             // [B]
    unsigned* __restrict__ flags,             // [B] magic completion flags
    float* __restrict__ out, int B)
{
    const int t = threadIdx.x;

    // ---------------- reducer block: overlapped final mean ----------------
    if ((int)blockIdx.x == B) {
        double x = 0.0;
        for (int idx = t; idx < B; idx += SS) {
            while (__hip_atomic_load(&flags[idx], __ATOMIC_ACQUIRE,
                                     __HIP_MEMORY_SCOPE_AGENT) != MAGIC)
                __builtin_amdgcn_s_sleep(2);
            const unsigned long long lb = __hip_atomic_load(
                (const unsigned long long*)&loss_ws[idx],
                __ATOMIC_RELAXED, __HIP_MEMORY_SCOPE_AGENT);
            x += __longlong_as_double((long long)lb);
        }
#pragma unroll
        for (int off = 1; off < 64; off <<= 1) x += __shfl_xor(x, off, 64);
        if (t == 0) out[0] = (float)(x / (double)B);
        return;
    }

    // ---------------- matcher block ----------------
    const int b = blockIdx.x;
    const float* ps = pred_strokes  + (size_t)b * SS * 10;
    const float* pv = pred_validity + (size_t)b * SS;
    const float* tg = targets      + (size_t)b * SS * 11;

    __shared__ double Cs[SS * SS];     // cost, f64, [compacted row][64]
    __shared__ int    col4row[SS];     // compacted gt-row -> pred col

    // --- per-lane gt row (slot t) in registers ---
    float tgv[11];
#pragma unroll
    for (int k = 0; k < 11; ++k) tgv[k] = tg[t * 11 + k];
    const float gv    = tgv[10];
    const bool  valid = gv > 0.5f;
    const unsigned long long vmask = __ballot(valid);
    const int ng = __popcll(vmask);

    // --- BCE term (slot t) ---
    double bterm;
    {
        const float pvv = pv[t];
        const float lp  = fmaxf(logf(pvv), -100.0f);
        const float l1p = fmaxf(logf(1.0f - pvv), -100.0f);
        bterm = -((double)gv * (double)lp + (double)(1.0f - gv) * (double)l1p);
    }

    double csum = 0.0, wsum = 0.0;

    if (ng > 0) {
        float pr[10];
#pragma unroll
        for (int k = 0; k < 10; ++k) pr[k] = ps[t * 10 + k];

        double u_reg = 0.0;                 // u[t+1] (lane t = compacted row t+1)
        double v_j   = 0.0;                 // v[t+1]
        int    p_j   = 0;                   // p[t+1]: matched compacted row
        unsigned long long colclaim = 0ull; // claimed-column mask (uniform)
        unsigned long long freerows = 0ull; // contested-row mask (uniform)
        unsigned long long vm = vmask;

        // --- cost build + claims, 2-row unrolled (claims in row order) ---
        int i = 0;
        while (i < ng) {
            const int vrow0 = __ffsll(vm) - 1; vm &= vm - 1;
            const bool pair = (i + 1 < ng);
            const int vrow1 = pair ? (__ffsll(vm) - 1) : vrow0;
            if (pair) vm &= vm - 1;

            float c0, c1;
            {
                float g0[10], g1[10], d0[10], d1[10];
#pragma unroll
                for (int k = 0; k < 10; ++k) {
                    g0[k] = __uint_as_float(
                        (unsigned)rlane_i(__float_as_int(tgv[k]), vrow0));
                    g1[k] = __uint_as_float(
                        (unsigned)rlane_i(__float_as_int(tgv[k]), vrow1));
                }
#pragma unroll
                for (int k = 0; k < 10; ++k) {
                    d0[k] = fabsf(pr[k] - g0[k]);
                    d1[k] = fabsf(pr[k] - g1[k]);
                }
                const float cs0 = ((d0[0] + d0[1]) + (d0[2] + d0[3]))
                                + ((d0[4] + d0[5]) + (d0[6] + d0[7]));
                const float cs1 = ((d1[0] + d1[1]) + (d1[2] + d1[3]))
                                + ((d1[4] + d1[5]) + (d1[6] + d1[7]));
                const float wd0 = d0[8] + d0[9];
                const float wd1 = d1[8] + d1[9];
                {
#pragma clang fp contract(off)
                    c0 = 5.0f * cs0 + wd0;   // numpy tree, mul-then-add
                    c1 = 5.0f * cs1 + wd1;
                }
            }
            Cs[i * SS + t] = (double)c0;
            if (pair) Cs[(i + 1) * SS + t] = (double)c1;

            // two independent row-min chains (interleaved by the scheduler)
            const unsigned k0 = __float_as_uint(c0);
            const unsigned k1 = __float_as_uint(c1);
            const unsigned m0 = (unsigned)rlane_i((int)wave_min_u32_to63(k0), 63);
            const unsigned m1 = (unsigned)rlane_i((int)wave_min_u32_to63(k1), 63);
            const unsigned long long b0 = __ballot(k0 == m0);
            const unsigned long long b1 = __ballot(k1 == m1);

            // claims in row order (bit-identical to the scalar loop)
            {
                const int jstar = __ffsll(b0) - 1;
                if (t == i) u_reg = (double)__uint_as_float(m0);
                if (!((colclaim >> jstar) & 1ull)) {
                    colclaim |= 1ull << jstar;
                    if (t == jstar) p_j = i + 1;
                } else {
                    freerows |= 1ull << i;
                }
            }
            if (pair) {
                const int jstar = __ffsll(b1) - 1;
                if (t == i + 1) u_reg = (double)__uint_as_float(m1);
                if (!((colclaim >> jstar) & 1ull)) {
                    colclaim |= 1ull << jstar;
                    if (t == jstar) p_j = i + 2;
                } else {
                    freerows |= 1ull << (i + 1);
                }
            }
            i += pair ? 2 : 1;
        }

        // --- Dijkstra phases for contested rows (key-first restructure) ---
        int nr0 = freerows ? (__ffsll(freerows) - 1) : -1;
        double Chead = (nr0 >= 0) ? Cs[nr0 * SS + t] : 0.0;

        while (freerows) {
            const int r0 = nr0;                    // 0-based root row, uniform
            freerows &= freerows - 1;
            nr0 = freerows ? (__ffsll(freerows) - 1) : -1;
            const int iph = r0 + 1;

            double   minv_j   = __builtin_inf();
            unsigned key_mv   = 0xFFFFFFFEu;       // key(+inf) = FFF00000|.. ;
                                                   // any first cur wins via <
            int      way_j    = 0;
            bool     used_j   = false;
            bool     row_used = (t == r0);         // p[0] = iph
            double   uv       = rlane_d(u_reg, r0) + v_j;  // u[root] + v[t+1]
            int      j0       = 0;
            double   Cval     = Chead;

            key_mv = f64hi_key(__builtin_inf());   // exact key of +inf

            // prefetch NEXT phase's head now; consumed after this phase
            const double Chead_next = (nr0 >= 0) ? Cs[nr0 * SS + t] : 0.0;

            for (;;) {
                if (t + 1 == j0) { used_j = true; key_mv = 0xFFFFFFFFu; }
                const double cur = Cval - uv;      // C - (u+v), uv-folded
                unsigned key_cur = f64hi_key(cur);
                if (used_j) key_cur = 0xFFFFFFFFu;
                const bool     upd = key_cur < key_mv;  // == (cur < minv)
                const unsigned key = upd ? key_cur : key_mv;

                // launch the chain immediately; f64 merge in its shadow
                const unsigned kc = wave_min_u32_to63(key);
                if (upd) { minv_j = cur; way_j = j0; }
                key_mv = key;

                const unsigned hstar = (unsigned)rlane_i((int)kc, 63);
                unsigned long long bal = __ballot(key == hstar);
                int j1 = __ffsll(bal);                       // col = lane+1
                int i1 = rlane_i(p_j, j1 - 1);               // p[j1]

                double C_next = 0.0;
                if (i1 != 0) C_next = Cs[(i1 - 1) * SS + t];

                const int hmin = (hstar & 0x80000000u)
                               ? (int)(hstar & 0x7FFFFFFFu) : (int)~hstar;
                int lmin;
                if (__popcll(bal) > 1) {   // rare: exact hi tie -> lo32
                    // tied lanes share the sign bit -> sign-mapped lo32
                    // comparison == full f64 comparison
                    const int      s31  = __double2hiint(minv_j) >> 31;
                    const unsigned lraw = (unsigned)__double2loint(minv_j);
                    const unsigned lo   = (key == hstar)
                                        ? (s31 ? ~lraw : lraw) : 0xFFFFFFFFu;
                    const unsigned lstar = (unsigned)rlane_i(
                        (int)wave_min_u32_to63(lo), 63);
                    bal  = __ballot(key == hstar && lo == lstar);
                    j1   = __ffsll(bal);
                    i1   = rlane_i(p_j, j1 - 1);
                    if (i1 != 0) C_next = Cs[(i1 - 1) * SS + t];
                    lmin = (hmin < 0) ? (int)~lstar : (int)lstar;
                } else {
                    lmin = rlane_i(__double2loint(minv_j), j1 - 1);
                }

                const double delta  = __hiloint2double(hmin, lmin);
                const double u_next = (i1 != 0) ? rlane_d(u_reg, i1 - 1) : 0.0;
                // (row i1 not yet row_used this iteration, so u_next is
                //  unaffected by the predicated add below.)

                if (row_used) u_reg += delta;     // u[p[used]] += delta
                if (used_j)   v_j   -= delta;     // v[used]    -= delta
                else          minv_j -= delta;    // minv[unused] -= delta
                row_used = row_used || (t == i1 - 1);

                // next iteration's key + uv: computed in the ds_read shadow
                if (!used_j) key_mv = f64hi_key(minv_j);
                uv = u_next + v_j;

                j0 = j1;
                if (i1 == 0) break;               // reached unmatched column
                Cval = C_next;
            }

            // --- augment along way[] (readlane pointer chase, short) ---
            int jj = j0;
            while (jj != 0) {
                const int jp   = rlane_i(way_j, jj - 1);
                const int pnew = (jp == 0) ? iph : rlane_i(p_j, jp - 1);
                if (t == jj - 1) p_j = pnew;
                jj = jp;
            }
            Chead = Chead_next;
        }

        // --- extract assignment ---
        if (p_j > 0) col4row[p_j - 1] = t;
        LDS_FENCE();

        // --- matched L1 sums: lane t handles its own valid gt slot ---
        if (valid) {
            const int r = __popcll(vmask & ((1ull << t) - 1ull)); // compacted
            const float* mp = ps + col4row[r] * 10;
#pragma unroll
            for (int k = 0; k < 8; ++k) csum += (double)fabsf(mp[k] - tgv[k]);
            wsum = (double)fabsf(mp[8] - tgv[8]) + (double)fabsf(mp[9] - tgv[9]);
        }
    }

    // --- wave reductions (cold path; identical to r7-r11 epilogue) ---
    double s0 = csum, s1 = wsum, s2 = bterm;
#pragma unroll
    for (int off = 1; off < 64; off <<= 1) {
        s0 += __shfl_xor(s0, off, 64);
        s1 += __shfl_xor(s1, off, 64);
        s2 += __shfl_xor(s2, off, 64);
    }

    if (t == 0) {
        const double bce = s2 / 64.0;
        const double loss = (ng > 0)
            ? 5.0 * (s0 / ((double)ng * 8.0)) + (s1 / ((double)ng * 2.0)) + bce
            : bce;
        __hip_atomic_store((unsigned long long*)&loss_ws[b],
                           (unsigned long long)__double_as_longlong(loss),
                           __ATOMIC_RELAXED, __HIP_MEMORY_SCOPE_AGENT);
        __hip_atomic_store(&flags[b], MAGIC,
                           __ATOMIC_RELEASE, __HIP_MEMORY_SCOPE_AGENT);
    }
}

extern "C" void kernel_launch(void* const* d_in, const int* in_sizes, int n_in,
                              void* d_out, int out_size, void* d_ws, size_t ws_size,
                              hipStream_t stream) {
    const float* ps = (const float*)d_in[0];
    const float* pv = (const float*)d_in[1];
    const float* tg = (const float*)d_in[2];
    float* out = (float*)d_out;
    const int B = in_sizes[0] / (SS * 10);

    double*   ws  = (double*)d_ws;
    unsigned* flg = (unsigned*)((char*)d_ws + (size_t)B * sizeof(double));

    detr_match_loss_kernel<<<B + 1, SS, 0, stream>>>(ps, pv, tg, ws, flg, out, B);
}